// Round 1
// baseline (1368.842 us; speedup 1.0000x reference)
//
#include <hip/hip_runtime.h>
#include <hip/hip_bf16.h>
#include <math.h>

// Problem constants
#define KN 2048      // num_embeddings
#define DN 256       // embedding_dim
#define NN 32768     // B*H*W
#define HW 1024      // H*W
#define XSTRIDE 260  // padded LDS row stride for x tile (floats)
#define ESTRIDE 36   // padded LDS row stride for E tile (floats)

// ws layout (bytes):
//   counts  int[2048]    @ 0       (zeroed each call)
//   lossacc float        @ 8192    (zeroed each call)
//   invne   double[2048] @ 16384
//   idx     int[32768]   @ 32768

// ---------------------------------------------------------------- col norms
__global__ __launch_bounds__(256) void k_colnorm(const float* __restrict__ E,
                                                 double* __restrict__ invne) {
  const int k = blockIdx.x * 256 + threadIdx.x;
  const float* p = E + k;
  double s = 0.0;
#pragma unroll 8
  for (int d = 0; d < DN; ++d) {
    double v = (double)p[(size_t)d * KN];
    s = fma(v, v, s);
  }
  double nrm = sqrt(s);
  if (nrm < 1e-12) nrm = 1e-12;
  invne[k] = 1.0 / nrm;
}

// ------------------------------------------------------- fused GEMM + argmax
// grid 1024, block 256. Each block: 32 rows x all 2048 cols.
// thread tile: 4 rows x 8 cols. E staged in 256-col x 32-d chunks.
__global__ __launch_bounds__(256) void k_argmax(const float* __restrict__ x,
                                                const float* __restrict__ E,
                                                const double* __restrict__ invne,
                                                int* __restrict__ idx_ws,
                                                float* __restrict__ fidx_out,
                                                int* __restrict__ counts) {
  __shared__ __align__(16) float xs[32 * XSTRIDE];  // 33,280 B
  __shared__ __align__(16) float es[256 * ESTRIDE]; // 36,864 B
  const int tid = threadIdx.x;
  const int rowbase = blockIdx.x * 32;

  // stage x tile: rows are strided by HW in global (d-major layout)
  {
    const int r = tid & 31;
    const int d0 = tid >> 5; // 0..7
    const int n = rowbase + r;
    const float* xb = x + (size_t)(n >> 10) * (DN * HW) + (n & 1023);
#pragma unroll
    for (int d = d0; d < DN; d += 8)
      xs[r * XSTRIDE + d] = xb[(size_t)d * HW];
  }

  const int row_g = tid >> 5; // 0..7 -> rows row_g*4 .. +3
  const int col_t = tid & 31; // cols col_t + 32*j

  double best[4];
  int bidx[4];
#pragma unroll
  for (int i = 0; i < 4; ++i) { best[i] = -1e300; bidx[i] = 0; }

  for (int kc = 0; kc < 8; ++kc) {
    const int kbase = kc * 256;
    float acc[4][8];
#pragma unroll
    for (int i = 0; i < 4; ++i)
#pragma unroll
      for (int j = 0; j < 8; ++j) acc[i][j] = 0.f;

    for (int dc = 0; dc < 8; ++dc) {
      const int db = dc * 32;
      __syncthreads(); // protect es readers of previous chunk (and xs staging)
      // stage E chunk: thread owns col c = tid, 32 d's, float4 LDS writes
      {
        const float* eb = E + (size_t)db * KN + kbase + tid;
#pragma unroll
        for (int q = 0; q < 8; ++q) {
          float4 v;
          v.x = eb[(size_t)(q * 4 + 0) * KN];
          v.y = eb[(size_t)(q * 4 + 1) * KN];
          v.z = eb[(size_t)(q * 4 + 2) * KN];
          v.w = eb[(size_t)(q * 4 + 3) * KN];
          *(float4*)(es + tid * ESTRIDE + q * 4) = v;
        }
      }
      __syncthreads();
      // micro-kernel: 8 d4-steps, 4x8 accs, float4 operands
#pragma unroll
      for (int t4 = 0; t4 < 8; ++t4) {
        float4 a[4], b[8];
#pragma unroll
        for (int i = 0; i < 4; ++i)
          a[i] = *(const float4*)(xs + (row_g * 4 + i) * XSTRIDE + db + t4 * 4);
#pragma unroll
        for (int j = 0; j < 8; ++j)
          b[j] = *(const float4*)(es + (col_t + 32 * j) * ESTRIDE + t4 * 4);
#pragma unroll
        for (int i = 0; i < 4; ++i)
#pragma unroll
          for (int j = 0; j < 8; ++j) {
            acc[i][j] += a[i].x * b[j].x;
            acc[i][j] += a[i].y * b[j].y;
            acc[i][j] += a[i].z * b[j].z;
            acc[i][j] += a[i].w * b[j].w;
          }
      }
    }
    // scale by exact inv-norm (f64) and update running argmax.
    // j ascending == col ascending, strict '>' keeps first max (argmin tie rule)
#pragma unroll
    for (int j = 0; j < 8; ++j) {
      const int c = kbase + col_t + 32 * j;
      const double s = invne[c];
#pragma unroll
      for (int i = 0; i < 4; ++i) {
        double v = (double)acc[i][j] * s;
        if (v > best[i]) { best[i] = v; bidx[i] = c; }
      }
    }
  }

  // cross-thread reduction over the 32 col-threads per row (reuse es)
  __syncthreads();
  double* redD = (double*)es;      // floats [0,2048) = 32*32 doubles
  int* redI = (int*)(es + 2048);   // floats [2048,3072)
#pragma unroll
  for (int i = 0; i < 4; ++i) {
    redD[(row_g * 4 + i) * 32 + col_t] = best[i];
    redI[(row_g * 4 + i) * 32 + col_t] = bidx[i];
  }
  __syncthreads();
  if (tid < 32) {
    const int r = tid;
    double bd = -1e300;
    int bi = 1 << 30;
    for (int t = 0; t < 32; ++t) {
      double dv = redD[r * 32 + t];
      int iv = redI[r * 32 + t];
      if (dv > bd || (dv == bd && iv < bi)) { bd = dv; bi = iv; }
    }
    const int n = rowbase + r;
    idx_ws[n] = bi;
    fidx_out[n] = (float)bi;
    atomicAdd(&counts[bi], 1);
  }
}

// ------------------------------------------------- gather + quantize + loss
__global__ __launch_bounds__(256) void k_quant(const float* __restrict__ x,
                                               const float* __restrict__ E,
                                               const int* __restrict__ idx,
                                               float* __restrict__ out,
                                               float* __restrict__ lossacc) {
  const int T = blockIdx.x * 256 + threadIdx.x; // 0 .. 2,097,151
  const int w4 = T & 7;
  int rest = T >> 3;
  const int h = rest & 31;
  rest >>= 5;
  const int d = rest & 255;
  const int b = rest >> 8;
  const int n = b * 1024 + h * 32 + w4 * 4;
  const int4 iv = *(const int4*)(idx + n);
  const size_t xoff = ((size_t)(b * 256 + d) << 10) + h * 32 + w4 * 4;
  const float4 xv = *(const float4*)(x + xoff);
  const float* Er = E + (size_t)d * KN;
  float4 q;
  q.x = Er[iv.x];
  q.y = Er[iv.y];
  q.z = Er[iv.z];
  q.w = Er[iv.w];
  *(float4*)(out + xoff) = q;
  const float dx = xv.x - q.x, dy = xv.y - q.y, dz = xv.z - q.z, dw = xv.w - q.w;
  float s = dx * dx + dy * dy + dz * dz + dw * dw;
#pragma unroll
  for (int off = 32; off > 0; off >>= 1) s += __shfl_down(s, off, 64);
  __shared__ float red[4];
  const int lane = threadIdx.x & 63, wv = threadIdx.x >> 6;
  if (lane == 0) red[wv] = s;
  __syncthreads();
  if (threadIdx.x == 0) atomicAdd(lossacc, red[0] + red[1] + red[2] + red[3]);
}

// -------------------------------------------------------- losses + entropy
__global__ __launch_bounds__(256) void k_final(const int* __restrict__ counts,
                                               const float* __restrict__ lossacc,
                                               float* __restrict__ out) {
  __shared__ double red[256];
  const int tid = threadIdx.x;
  double t = 0.0;
  for (int u = tid; u < KN; u += 256) {
    float p = (float)counts[u] * (1.0f / 32768.0f);
    t += (double)(p * logf(p + 1e-10f));
  }
  red[tid] = t;
  __syncthreads();
  for (int s2 = 128; s2 > 0; s2 >>= 1) {
    if (tid < s2) red[tid] += red[tid + s2];
    __syncthreads();
  }
  if (tid == 0) {
    float L = lossacc[0] * (1.0f / 8388608.0f);
    out[8388608] = L; // dictionary_loss
    out[8388609] = L; // commitment_loss (identical in forward)
    out[8388610] = (float)red[0];
  }
}

extern "C" void kernel_launch(void* const* d_in, const int* in_sizes, int n_in,
                              void* d_out, int out_size, void* d_ws, size_t ws_size,
                              hipStream_t stream) {
  const float* x = (const float*)d_in[0];
  const float* E = (const float*)d_in[1];
  float* out = (float*)d_out;
  char* ws = (char*)d_ws;
  int* counts = (int*)ws;
  float* lossacc = (float*)(ws + 8192);
  double* invne = (double*)(ws + 16384);
  int* idx = (int*)(ws + 32768);

  hipMemsetAsync(ws, 0, 8448, stream); // counts + lossacc
  k_colnorm<<<KN / 256, 256, 0, stream>>>(E, invne);
  k_argmax<<<NN / 32, 256, 0, stream>>>(x, E, invne, idx, out + 8388611, counts);
  k_quant<<<(NN * DN / 4) / 256, 256, 0, stream>>>(x, E, idx, out, lossacc);
  k_final<<<1, 256, 0, stream>>>(counts, lossacc, out);
}

// Round 2
// 1049.221 us; speedup vs baseline: 1.3046x; 1.3046x over previous
//
#include <hip/hip_runtime.h>
#include <hip/hip_bf16.h>
#include <math.h>

// Problem constants
#define KN 2048      // num_embeddings
#define DN 256       // embedding_dim
#define NN 32768     // B*H*W
#define HW 1024      // H*W
#define XSTRIDE 260  // padded LDS row stride for x tile (floats)

// ws layout (bytes):
//   counts  int[2048]    @ 0       (zeroed each call)
//   lossacc float        @ 8192    (zeroed each call)
//   invne   double[2048] @ 16384
//   idx     int[32768]   @ 32768

// ---------------------------------------------------------------- col norms
__global__ __launch_bounds__(256) void k_colnorm(const float* __restrict__ E,
                                                 double* __restrict__ invne) {
  const int k = blockIdx.x * 256 + threadIdx.x;
  const float* p = E + k;
  double s = 0.0;
#pragma unroll 8
  for (int d = 0; d < DN; ++d) {
    double v = (double)p[(size_t)d * KN];
    s = fma(v, v, s);
  }
  double nrm = sqrt(s);
  if (nrm < 1e-12) nrm = 1e-12;
  invne[k] = 1.0 / nrm;
}

// ------------------------------------------------------- fused GEMM + argmax
// grid 1024, block 256. Each block: 32 rows x all 2048 cols.
// thread tile: 4 rows x 8 cols. E staged in 256-col x 32-d chunks,
// LDS layout [t4][col][4] so wave reads are lane-contiguous (conflict-free).
// Chunk ch = kc*8 + dc; E for chunk ch+1 is register-prefetched during
// compute of chunk ch (latency hidden under FMAs).

#define LOADCH(r, ch)                                              \
  {                                                                \
    const int kb_ = ((ch) >> 3) * 256;                             \
    const int db_ = ((ch) & 7) * 32;                               \
    const float* eb_ = E + (size_t)db_ * KN + kb_ + tid;           \
    _Pragma("unroll") for (int q = 0; q < 32; ++q)                 \
        r[q] = eb_[(size_t)q * KN];                                \
  }

#define WRITECH(r)                                                 \
  {                                                                \
    _Pragma("unroll") for (int q = 0; q < 8; ++q) {                \
      float4 v_;                                                   \
      v_.x = r[4 * q + 0];                                         \
      v_.y = r[4 * q + 1];                                         \
      v_.z = r[4 * q + 2];                                         \
      v_.w = r[4 * q + 3];                                         \
      *(float4*)(es + (((q) << 8) + tid) * 4) = v_;                \
    }                                                              \
  }

#define COMPUTECH(ch)                                              \
  {                                                                \
    const int db_ = ((ch) & 7) * 32;                               \
    _Pragma("unroll") for (int t4 = 0; t4 < 8; ++t4) {             \
      float4 a_[4], b_[8];                                         \
      _Pragma("unroll") for (int i = 0; i < 4; ++i)                \
          a_[i] = *(const float4*)(xs + (row_g * 4 + i) * XSTRIDE  \
                                   + db_ + t4 * 4);                \
      _Pragma("unroll") for (int j = 0; j < 8; ++j)                \
          b_[j] = *(const float4*)(es + ((t4 << 8) + col_t         \
                                         + 32 * j) * 4);           \
      _Pragma("unroll") for (int i = 0; i < 4; ++i)                \
          _Pragma("unroll") for (int j = 0; j < 8; ++j) {          \
        acc[i][j] += a_[i].x * b_[j].x;                            \
        acc[i][j] += a_[i].y * b_[j].y;                            \
        acc[i][j] += a_[i].z * b_[j].z;                            \
        acc[i][j] += a_[i].w * b_[j].w;                            \
      }                                                            \
    }                                                              \
  }

__global__ __launch_bounds__(256) void k_argmax(const float* __restrict__ x,
                                                const float* __restrict__ E,
                                                const double* __restrict__ invne,
                                                int* __restrict__ idx_ws,
                                                float* __restrict__ fidx_out,
                                                int* __restrict__ counts) {
  __shared__ __align__(16) float xs[32 * XSTRIDE];   // 33,280 B
  __shared__ __align__(16) float es[8 * 256 * 4];    // 32,768 B [t4][col][4]
  const int tid = threadIdx.x;
  const int rowbase = blockIdx.x * 32;

  // stage x tile: rows are strided by HW in global (d-major layout)
  {
    const int r = tid & 31;
    const int d0 = tid >> 5; // 0..7
    const int n = rowbase + r;
    const float* xb = x + (size_t)(n >> 10) * (DN * HW) + (n & 1023);
#pragma unroll
    for (int d = d0; d < DN; d += 8)
      xs[r * XSTRIDE + d] = xb[(size_t)d * HW];
  }
  // xs readers first touch it after the barriers in the chunk loop -> safe.

  const int row_g = tid >> 5; // 0..7 -> rows row_g*4 .. +3
  const int col_t = tid & 31; // cols col_t + 32*j

  double best[4];
  int bidx[4];
#pragma unroll
  for (int i = 0; i < 4; ++i) { best[i] = -1e300; bidx[i] = 0; }

  float acc[4][8];
  float rA[32], rB[32];

  LOADCH(rA, 0);

  for (int ch2 = 0; ch2 < 32; ++ch2) {
    const int chA = ch2 * 2;
    const int chB = chA + 1;

    // ---- phase A (even chunk)
    if ((chA & 7) == 0) {
#pragma unroll
      for (int i = 0; i < 4; ++i)
#pragma unroll
        for (int j = 0; j < 8; ++j) acc[i][j] = 0.f;
    }
    __syncthreads();            // readers of previous chunk done
    WRITECH(rA);
    __syncthreads();            // es ready
    LOADCH(rB, chB);            // prefetch next chunk under compute
    COMPUTECH(chA);

    // ---- phase B (odd chunk)
    __syncthreads();
    WRITECH(rB);
    __syncthreads();
    if (chB < 63) { LOADCH(rA, chB + 1); }
    COMPUTECH(chB);

    if ((chB & 7) == 7) {
      const int kbase = (chB >> 3) * 256;
      // j ascending == col ascending, strict '>' keeps first max
#pragma unroll
      for (int j = 0; j < 8; ++j) {
        const int c = kbase + col_t + 32 * j;
        const double s = invne[c];
#pragma unroll
        for (int i = 0; i < 4; ++i) {
          double v = (double)acc[i][j] * s;
          if (v > best[i]) { best[i] = v; bidx[i] = c; }
        }
      }
    }
  }

  // cross-thread reduction over the 32 col-threads per row (reuse es)
  __syncthreads();
  double* redD = (double*)es;      // floats [0,2048) = 32*32 doubles
  int* redI = (int*)(es + 2048);   // floats [2048,3072)
#pragma unroll
  for (int i = 0; i < 4; ++i) {
    redD[(row_g * 4 + i) * 32 + col_t] = best[i];
    redI[(row_g * 4 + i) * 32 + col_t] = bidx[i];
  }
  __syncthreads();
  if (tid < 32) {
    const int r = tid;
    double bd = -1e300;
    int bi = 1 << 30;
    for (int t = 0; t < 32; ++t) {
      double dv = redD[r * 32 + t];
      int iv = redI[r * 32 + t];
      if (dv > bd || (dv == bd && iv < bi)) { bd = dv; bi = iv; }
    }
    const int n = rowbase + r;
    idx_ws[n] = bi;
    fidx_out[n] = (float)bi;
    atomicAdd(&counts[bi], 1);
  }
}

// ------------------------------------------------- gather + quantize + loss
__global__ __launch_bounds__(256) void k_quant(const float* __restrict__ x,
                                               const float* __restrict__ E,
                                               const int* __restrict__ idx,
                                               float* __restrict__ out,
                                               float* __restrict__ lossacc) {
  const int T = blockIdx.x * 256 + threadIdx.x; // 0 .. 2,097,151
  const int w4 = T & 7;
  int rest = T >> 3;
  const int h = rest & 31;
  rest >>= 5;
  const int d = rest & 255;
  const int b = rest >> 8;
  const int n = b * 1024 + h * 32 + w4 * 4;
  const int4 iv = *(const int4*)(idx + n);
  const size_t xoff = ((size_t)(b * 256 + d) << 10) + h * 32 + w4 * 4;
  const float4 xv = *(const float4*)(x + xoff);
  const float* Er = E + (size_t)d * KN;
  float4 q;
  q.x = Er[iv.x];
  q.y = Er[iv.y];
  q.z = Er[iv.z];
  q.w = Er[iv.w];
  *(float4*)(out + xoff) = q;
  const float dx = xv.x - q.x, dy = xv.y - q.y, dz = xv.z - q.z, dw = xv.w - q.w;
  float s = dx * dx + dy * dy + dz * dz + dw * dw;
#pragma unroll
  for (int off = 32; off > 0; off >>= 1) s += __shfl_down(s, off, 64);
  __shared__ float red[4];
  const int lane = threadIdx.x & 63, wv = threadIdx.x >> 6;
  if (lane == 0) red[wv] = s;
  __syncthreads();
  if (threadIdx.x == 0) atomicAdd(lossacc, red[0] + red[1] + red[2] + red[3]);
}

// -------------------------------------------------------- losses + entropy
__global__ __launch_bounds__(256) void k_final(const int* __restrict__ counts,
                                               const float* __restrict__ lossacc,
                                               float* __restrict__ out) {
  __shared__ double red[256];
  const int tid = threadIdx.x;
  double t = 0.0;
  for (int u = tid; u < KN; u += 256) {
    float p = (float)counts[u] * (1.0f / 32768.0f);
    t += (double)(p * logf(p + 1e-10f));
  }
  red[tid] = t;
  __syncthreads();
  for (int s2 = 128; s2 > 0; s2 >>= 1) {
    if (tid < s2) red[tid] += red[tid + s2];
    __syncthreads();
  }
  if (tid == 0) {
    float L = lossacc[0] * (1.0f / 8388608.0f);
    out[8388608] = L; // dictionary_loss
    out[8388609] = L; // commitment_loss (identical in forward)
    out[8388610] = (float)red[0];
  }
}

extern "C" void kernel_launch(void* const* d_in, const int* in_sizes, int n_in,
                              void* d_out, int out_size, void* d_ws, size_t ws_size,
                              hipStream_t stream) {
  const float* x = (const float*)d_in[0];
  const float* E = (const float*)d_in[1];
  float* out = (float*)d_out;
  char* ws = (char*)d_ws;
  int* counts = (int*)ws;
  float* lossacc = (float*)(ws + 8192);
  double* invne = (double*)(ws + 16384);
  int* idx = (int*)(ws + 32768);

  hipMemsetAsync(ws, 0, 8448, stream); // counts + lossacc
  k_colnorm<<<KN / 256, 256, 0, stream>>>(E, invne);
  k_argmax<<<NN / 32, 256, 0, stream>>>(x, E, invne, idx, out + 8388611, counts);
  k_quant<<<(NN * DN / 4) / 256, 256, 0, stream>>>(x, E, idx, out, lossacc);
  k_final<<<1, 256, 0, stream>>>(counts, lossacc, out);
}

// Round 3
// 334.656 us; speedup vs baseline: 4.0903x; 3.1352x over previous
//
#include <hip/hip_runtime.h>
#include <hip/hip_bf16.h>
#include <hip/hip_fp16.h>
#include <math.h>

// Problem constants
#define KN 2048      // num_embeddings (GEMM N)
#define DN 256       // embedding_dim  (GEMM K)
#define NN 32768     // B*H*W          (GEMM M)
#define HW 1024      // H*W
#define XSTR 260     // padded LDS row stride for x tile (floats)

typedef _Float16 half8 __attribute__((ext_vector_type(8)));
typedef float floatx4 __attribute__((ext_vector_type(4)));

// ws layout (bytes):
//   counts  int[2048]      @ 0        (zeroed each call)
//   lossacc float          @ 8192     (zeroed each call)
//   invne   double[2048]   @ 16384
//   idx     int[32768]     @ 32768
//   Eh      f16[524288]    @ 163840   (1 MB)  staging-order hi table
//   El      f16[524288]    @ 1212416  (1 MB)  staging-order lo table (x4096)

// ---------------------------------------------------------------- col norms
__global__ __launch_bounds__(256) void k_colnorm(const float* __restrict__ E,
                                                 double* __restrict__ invne) {
  const int k = blockIdx.x * 256 + threadIdx.x;
  const float* p = E + k;
  double s = 0.0;
#pragma unroll 8
  for (int d = 0; d < DN; ++d) {
    double v = (double)p[(size_t)d * KN];
    s = fma(v, v, s);
  }
  double nrm = sqrt(s);
  if (nrm < 1e-12) nrm = 1e-12;
  invne[k] = 1.0 / nrm;
}

// --------------------------------------------- E -> f16 hi/lo, staging order
// Target layout, f16 units: chunk t = nc*4+ks (nc: 128-col group, ks: 64-d group)
//   off = t*8192 + (kg*128 + cl)*8 + k0   with d = ks*64 + kg*8 + k0, cl = c&127
__global__ __launch_bounds__(256) void k_convE(const float* __restrict__ E,
                                               _Float16* __restrict__ Eh,
                                               _Float16* __restrict__ El) {
  const int c = ((blockIdx.x & 7) << 8) + threadIdx.x; // 0..2047
  const int dg = blockIdx.x >> 3;                      // 0..31 (8-d groups)
  const int ks = dg >> 3, kg = dg & 7;
  const int nc = c >> 7, cl = c & 127;
  const size_t off = (size_t)(nc * 4 + ks) * 8192 + (size_t)(kg * 128 + cl) * 8;
  half8 hv, lv;
#pragma unroll
  for (int j = 0; j < 8; ++j) {
    float v = E[(size_t)(dg * 8 + j) * KN + c];
    _Float16 h = (_Float16)v;
    hv[j] = h;
    lv[j] = (_Float16)((v - (float)h) * 4096.0f);
  }
  *(half8*)(Eh + off) = hv;
  *(half8*)(El + off) = lv;
}

// -------------------------------------------------- async global->LDS helper
__device__ __forceinline__ void gload_lds16(const void* g, void* l) {
  __builtin_amdgcn_global_load_lds(
      (const __attribute__((address_space(1))) unsigned int*)g,
      (__attribute__((address_space(3))) unsigned int*)l, 16, 0, 0);
}

// ----------------------------------------------- fused MFMA GEMM^3 + argmax
// grid 1024 blocks x 256 thr (4 waves). Block: 32 rows x all 2048 cols.
// Wave w owns cols [nc*128 + w*32, +32) per n-chunk; 2x2 16x16 frags.
// A (x tile, hi/lo f16) fully in registers; B double-buffered in LDS.
#define STAGE(t, buf)                                                      \
  {                                                                        \
    const size_t so_ = (size_t)(t) * 8192;                                 \
    _Float16* db_ = (_Float16*)lds + (buf) * 16384;                        \
    _Pragma("unroll") for (int q_ = 0; q_ < 4; ++q_) {                     \
      const int ei_ = (q_ * 256 + tid) * 8;                                \
      gload_lds16(Eh + so_ + ei_, db_ + ei_);                              \
      gload_lds16(El + so_ + ei_, db_ + 8192 + ei_);                       \
    }                                                                      \
  }

__global__ __launch_bounds__(256, 2) void k_score(
    const float* __restrict__ x, const _Float16* __restrict__ Eh,
    const _Float16* __restrict__ El, const double* __restrict__ invne,
    int* __restrict__ idx_ws, float* __restrict__ fidx_out,
    int* __restrict__ counts) {
  __shared__ __align__(16) char lds[65536];
  const int tid = threadIdx.x;
  const int lane = tid & 63;
  const int w = tid >> 6;
  const int rowbase = blockIdx.x * 32;

  // ---- stage x tile (f32) into LDS [32][XSTR]
  {
    float* xs = (float*)lds;
    const int r = tid & 31;
    const int d0 = tid >> 5;
    const int n = rowbase + r;
    const float* xb = x + (size_t)(n >> 10) * (DN * HW) + (n & 1023);
#pragma unroll
    for (int d = d0; d < DN; d += 8)
      xs[r * XSTR + d] = xb[(size_t)d * HW];
  }
  __syncthreads();

  // ---- build A fragments in regs: row=lane&15 (+16*mf), k=kI*32+(lane>>4)*8+i
  half8 ah[2][8], al[2][8];
  {
    const float* xs = (const float*)lds;
#pragma unroll
    for (int mf = 0; mf < 2; ++mf)
#pragma unroll
      for (int kI = 0; kI < 8; ++kI) {
        const float* p = xs + (mf * 16 + (lane & 15)) * XSTR + kI * 32 + (lane >> 4) * 8;
        half8 h, l;
#pragma unroll
        for (int i = 0; i < 8; ++i) {
          float v = p[i];
          _Float16 hh = (_Float16)v;
          h[i] = hh;
          l[i] = (_Float16)((v - (float)hh) * 4096.0f);
        }
        ah[mf][kI] = h;
        al[mf][kI] = l;
      }
  }
  __syncthreads(); // xs dead; LDS becomes B double-buffer

  double best[2][4];
  int bidx[2][4];
#pragma unroll
  for (int mf = 0; mf < 2; ++mf)
#pragma unroll
    for (int r = 0; r < 4; ++r) { best[mf][r] = -1e300; bidx[mf][r] = 0; }

  STAGE(0, 0);
  __syncthreads();

  for (int nc = 0; nc < 16; ++nc) {
    floatx4 accm[2][2], accc[2][2];
#pragma unroll
    for (int mf = 0; mf < 2; ++mf)
#pragma unroll
      for (int nf = 0; nf < 2; ++nf) { accm[mf][nf] = (floatx4)0.0f; accc[mf][nf] = (floatx4)0.0f; }

#pragma unroll
    for (int ks = 0; ks < 4; ++ks) {
      const int t = nc * 4 + ks;
      if (t < 63) STAGE(t + 1, (ks & 1) ^ 1);
      const _Float16* Bh = (const _Float16*)lds + (ks & 1) * 16384;
#pragma unroll
      for (int ki = 0; ki < 2; ++ki) {
        const int kI = ks * 2 + ki;
        half8 bh[2], bl[2];
#pragma unroll
        for (int nf = 0; nf < 2; ++nf) {
          const int colc = w * 32 + nf * 16 + (lane & 15);
          const int kg = ki * 4 + (lane >> 4);
          const _Float16* bp = Bh + (size_t)(kg * 128 + colc) * 8;
          bh[nf] = *(const half8*)bp;
          bl[nf] = *(const half8*)(bp + 8192);
        }
#pragma unroll
        for (int mf = 0; mf < 2; ++mf)
#pragma unroll
          for (int nf = 0; nf < 2; ++nf) {
            accm[mf][nf] = __builtin_amdgcn_mfma_f32_16x16x32_f16(ah[mf][kI], bh[nf], accm[mf][nf], 0, 0, 0);
            accc[mf][nf] = __builtin_amdgcn_mfma_f32_16x16x32_f16(ah[mf][kI], bl[nf], accc[mf][nf], 0, 0, 0);
            accc[mf][nf] = __builtin_amdgcn_mfma_f32_16x16x32_f16(al[mf][kI], bh[nf], accc[mf][nf], 0, 0, 0);
          }
      }
      __syncthreads();
    }

    // epilogue: scale by f64 inv-norm, update running argmax (cols ascending)
#pragma unroll
    for (int nf = 0; nf < 2; ++nf) {
      const int c = nc * 128 + w * 32 + nf * 16 + (lane & 15);
      const double sv = invne[c];
#pragma unroll
      for (int mf = 0; mf < 2; ++mf)
#pragma unroll
        for (int r = 0; r < 4; ++r) {
          const double s =
              ((double)accm[mf][nf][r] + (double)accc[mf][nf][r] * (1.0 / 4096.0)) * sv;
          if (s > best[mf][r]) { best[mf][r] = s; bidx[mf][r] = c; }
        }
    }
  }

  // ---- final reduction: 64 (wave,col-lane) entries per row
  __syncthreads();
  double* redD = (double*)lds;          // 32*64 doubles = 16 KB
  int* redI = (int*)(lds + 16384);      // 8 KB
  const int ent = w * 16 + (lane & 15);
#pragma unroll
  for (int mf = 0; mf < 2; ++mf)
#pragma unroll
    for (int r = 0; r < 4; ++r) {
      const int row = mf * 16 + (lane >> 4) * 4 + r;
      redD[row * 64 + ent] = best[mf][r];
      redI[row * 64 + ent] = bidx[mf][r];
    }
  __syncthreads();
  if (tid < 32) {
    double bd = -1e300;
    int bi = 1 << 30;
    for (int e = 0; e < 64; ++e) {
      double dv = redD[tid * 64 + e];
      int iv = redI[tid * 64 + e];
      if (dv > bd || (dv == bd && iv < bi)) { bd = dv; bi = iv; }
    }
    const int n = rowbase + tid;
    idx_ws[n] = bi;
    fidx_out[n] = (float)bi;
    atomicAdd(&counts[bi], 1);
  }
}

// ------------------------------------------------- gather + quantize + loss
__global__ __launch_bounds__(256) void k_quant(const float* __restrict__ x,
                                               const float* __restrict__ E,
                                               const int* __restrict__ idx,
                                               float* __restrict__ out,
                                               float* __restrict__ lossacc) {
  const int T = blockIdx.x * 256 + threadIdx.x;
  const int w4 = T & 7;
  int rest = T >> 3;
  const int h = rest & 31;
  rest >>= 5;
  const int d = rest & 255;
  const int b = rest >> 8;
  const int n = b * 1024 + h * 32 + w4 * 4;
  const int4 iv = *(const int4*)(idx + n);
  const size_t xoff = ((size_t)(b * 256 + d) << 10) + h * 32 + w4 * 4;
  const float4 xv = *(const float4*)(x + xoff);
  const float* Er = E + (size_t)d * KN;
  float4 q;
  q.x = Er[iv.x];
  q.y = Er[iv.y];
  q.z = Er[iv.z];
  q.w = Er[iv.w];
  *(float4*)(out + xoff) = q;
  const float dx = xv.x - q.x, dy = xv.y - q.y, dz = xv.z - q.z, dw = xv.w - q.w;
  float s = dx * dx + dy * dy + dz * dz + dw * dw;
#pragma unroll
  for (int off = 32; off > 0; off >>= 1) s += __shfl_down(s, off, 64);
  __shared__ float red[4];
  const int lane = threadIdx.x & 63, wv = threadIdx.x >> 6;
  if (lane == 0) red[wv] = s;
  __syncthreads();
  if (threadIdx.x == 0) atomicAdd(lossacc, red[0] + red[1] + red[2] + red[3]);
}

// -------------------------------------------------------- losses + entropy
__global__ __launch_bounds__(256) void k_final(const int* __restrict__ counts,
                                               const float* __restrict__ lossacc,
                                               float* __restrict__ out) {
  __shared__ double red[256];
  const int tid = threadIdx.x;
  double t = 0.0;
  for (int u = tid; u < KN; u += 256) {
    float p = (float)counts[u] * (1.0f / 32768.0f);
    t += (double)(p * logf(p + 1e-10f));
  }
  red[tid] = t;
  __syncthreads();
  for (int s2 = 128; s2 > 0; s2 >>= 1) {
    if (tid < s2) red[tid] += red[tid + s2];
    __syncthreads();
  }
  if (tid == 0) {
    float L = lossacc[0] * (1.0f / 8388608.0f);
    out[8388608] = L; // dictionary_loss
    out[8388609] = L; // commitment_loss (identical in forward)
    out[8388610] = (float)red[0];
  }
}

extern "C" void kernel_launch(void* const* d_in, const int* in_sizes, int n_in,
                              void* d_out, int out_size, void* d_ws, size_t ws_size,
                              hipStream_t stream) {
  const float* x = (const float*)d_in[0];
  const float* E = (const float*)d_in[1];
  float* out = (float*)d_out;
  char* ws = (char*)d_ws;
  int* counts = (int*)ws;
  float* lossacc = (float*)(ws + 8192);
  double* invne = (double*)(ws + 16384);
  int* idx = (int*)(ws + 32768);
  _Float16* Eh = (_Float16*)(ws + 163840);
  _Float16* El = (_Float16*)(ws + 1212416);

  hipMemsetAsync(ws, 0, 8448, stream); // counts + lossacc
  k_colnorm<<<KN / 256, 256, 0, stream>>>(E, invne);
  k_convE<<<256, 256, 0, stream>>>(E, Eh, El);
  k_score<<<NN / 32, 256, 0, stream>>>(x, Eh, El, invne, idx, out + 8388611, counts);
  k_quant<<<(NN * DN / 4) / 256, 256, 0, stream>>>(x, E, idx, out, lossacc);
  k_final<<<1, 256, 0, stream>>>(counts, lossacc, out);
}

// Round 4
// 329.660 us; speedup vs baseline: 4.1523x; 1.0152x over previous
//
#include <hip/hip_runtime.h>
#include <hip/hip_bf16.h>
#include <hip/hip_fp16.h>
#include <math.h>

// Problem constants
#define KN 2048      // num_embeddings (GEMM N)
#define DN 256       // embedding_dim  (GEMM K)
#define NN 32768     // B*H*W          (GEMM M)
#define HW 1024      // H*W
#define XSTR 260     // padded LDS row stride for x tile (floats)

typedef _Float16 half8 __attribute__((ext_vector_type(8)));
typedef float floatx4 __attribute__((ext_vector_type(4)));

// ws layout (bytes):
//   counts    int[2048]     @ 0        (zeroed each call)
//   lossparts float[256]    @ 8192     (zeroed each call)
//   norminv   double[2048]  @ 16384    (zeroed, then normsq, then 1/norm)
//   idx       int[32768]    @ 32768
//   Et        f16[1048576]  @ 163840   (2 MB) fragment-order hi/lo table,
//              pre-scaled by 1/||col||: chunk (t*4+w) of 4096 halfs =
//              [hi: (kg*32+col)*8+k0][lo: +2048], d = ks*64+kg*8+k0, t=nc*4+ks

// ------------------------------------------------- column norms (partials)
__global__ __launch_bounds__(256) void k_norm(const float* __restrict__ E,
                                              double* __restrict__ normsq) {
  const int c = ((blockIdx.x & 7) << 8) + threadIdx.x;  // 0..2047
  const int dseg = blockIdx.x >> 3;                     // 0..7 (32 d's each)
  const float* p = E + (size_t)(dseg * 32) * KN + c;
  double s = 0.0;
#pragma unroll 8
  for (int d = 0; d < 32; ++d) {
    double v = (double)p[(size_t)d * KN];
    s = fma(v, v, s);
  }
  atomicAdd(&normsq[c], s);
}

__global__ __launch_bounds__(256) void k_inv(double* __restrict__ norminv) {
  const int c = blockIdx.x * 256 + threadIdx.x;
  double nr = sqrt(norminv[c]);
  if (nr < 1e-12) nr = 1e-12;
  norminv[c] = 1.0 / nr;
}

// --------------------- E -> normalized f16 hi/lo, fragment order (see ws map)
__global__ __launch_bounds__(256) void k_convE(const float* __restrict__ E,
                                               const double* __restrict__ norminv,
                                               _Float16* __restrict__ Et) {
  const int c = ((blockIdx.x & 7) << 8) + threadIdx.x;  // 0..2047
  const int dg = blockIdx.x >> 3;                       // 0..31 (8-d groups)
  const int ks = dg >> 3, kg = dg & 7;
  const int nc = c >> 7, w = (c >> 5) & 3, col = c & 31;
  const double inv = norminv[c];
  const size_t base = (size_t)((nc * 4 + ks) * 4 + w) * 4096 + (size_t)(kg * 32 + col) * 8;
  half8 hv, lv;
#pragma unroll
  for (int j = 0; j < 8; ++j) {
    float v = (float)((double)E[(size_t)(dg * 8 + j) * KN + c] * inv);
    _Float16 h = (_Float16)v;
    hv[j] = h;
    lv[j] = (_Float16)((v - (float)h) * 4096.0f);
  }
  *(half8*)(Et + base) = hv;
  *(half8*)(Et + base + 2048) = lv;
}

// ----------------------------------------------- fused MFMA GEMM^3 + argmax
// grid 1024 x 256 thr (4 waves). Block: 32 rows x 2048 cols. Wave w owns
// cols [nc*128 + w*32, +32): B frags loaded global->reg (no LDS, no barriers
// in the main loop). A (x hi/lo) fully in registers.
struct BF {
  half8 h[2][2];  // [ki][nf]
  half8 l[2][2];
};

__device__ __forceinline__ BF loadB(const _Float16* __restrict__ Et, int t,
                                    int w, int lg, int c16) {
  BF b;
  const _Float16* p = Et + ((size_t)(t * 4 + w) << 12);
#pragma unroll
  for (int ki = 0; ki < 2; ++ki)
#pragma unroll
    for (int nf = 0; nf < 2; ++nf) {
      const int off = ((ki * 4 + lg) * 32 + nf * 16 + c16) * 8;
      b.h[ki][nf] = *(const half8*)(p + off);
      b.l[ki][nf] = *(const half8*)(p + 2048 + off);
    }
  return b;
}

#define COMP(ks, b)                                                          \
  {                                                                          \
    __builtin_amdgcn_s_setprio(1);                                           \
    _Pragma("unroll") for (int ki = 0; ki < 2; ++ki)                         \
        _Pragma("unroll") for (int mf = 0; mf < 2; ++mf)                     \
            _Pragma("unroll") for (int nf = 0; nf < 2; ++nf) {               \
      accm[mf][nf] = __builtin_amdgcn_mfma_f32_16x16x32_f16(                 \
          ah[mf][(ks)*2 + ki], (b).h[ki][nf], accm[mf][nf], 0, 0, 0);        \
      accc[mf][nf] = __builtin_amdgcn_mfma_f32_16x16x32_f16(                 \
          ah[mf][(ks)*2 + ki], (b).l[ki][nf], accc[mf][nf], 0, 0, 0);        \
      accc[mf][nf] = __builtin_amdgcn_mfma_f32_16x16x32_f16(                 \
          al[mf][(ks)*2 + ki], (b).h[ki][nf], accc[mf][nf], 0, 0, 0);        \
    }                                                                        \
    __builtin_amdgcn_s_setprio(0);                                           \
  }

__global__ __launch_bounds__(256, 2) void k_score(
    const float* __restrict__ x, const _Float16* __restrict__ Et,
    int* __restrict__ idx_ws, float* __restrict__ fidx_out,
    int* __restrict__ counts) {
  __shared__ __align__(16) char lds[33536];
  const int tid = threadIdx.x;
  const int lane = tid & 63;
  const int w = tid >> 6;
  const int lg = lane >> 4;
  const int c16 = lane & 15;
  const int rowbase = blockIdx.x * 32;

  // ---- stage x tile (f32) into LDS [32][XSTR]
  {
    float* xs = (float*)lds;
    const int r = tid & 31;
    const int d0 = tid >> 5;
    const int n = rowbase + r;
    const float* xb = x + (size_t)(n >> 10) * (DN * HW) + (n & 1023);
#pragma unroll
    for (int d = d0; d < DN; d += 8)
      xs[r * XSTR + d] = xb[(size_t)d * HW];
  }
  __syncthreads();

  // ---- build A fragments: row=lane&15 (+16*mf), k=kI*32+lg*8+i
  half8 ah[2][8], al[2][8];
  {
    const float* xs = (const float*)lds;
#pragma unroll
    for (int mf = 0; mf < 2; ++mf)
#pragma unroll
      for (int kI = 0; kI < 8; ++kI) {
        const float* p = xs + (mf * 16 + c16) * XSTR + kI * 32 + lg * 8;
        half8 h, l;
#pragma unroll
        for (int i = 0; i < 8; ++i) {
          float v = p[i];
          _Float16 hh = (_Float16)v;
          h[i] = hh;
          l[i] = (_Float16)((v - (float)hh) * 4096.0f);
        }
        ah[mf][kI] = h;
        al[mf][kI] = l;
      }
  }

  double best[2][4];
  int bidx[2][4];
#pragma unroll
  for (int mf = 0; mf < 2; ++mf)
#pragma unroll
    for (int r = 0; r < 4; ++r) { best[mf][r] = -1e300; bidx[mf][r] = 0; }

  BF b0 = loadB(Et, 0, w, lg, c16);
  BF bn;

#pragma unroll 2
  for (int nc = 0; nc < 16; ++nc) {
    const int t0 = nc * 4;
    floatx4 accm[2][2], accc[2][2];
#pragma unroll
    for (int mf = 0; mf < 2; ++mf)
#pragma unroll
      for (int nf = 0; nf < 2; ++nf) {
        accm[mf][nf] = (floatx4)0.0f;
        accc[mf][nf] = (floatx4)0.0f;
      }

    bn = loadB(Et, t0 + 1, w, lg, c16);
    COMP(0, b0);
    b0 = bn;
    bn = loadB(Et, t0 + 2, w, lg, c16);
    COMP(1, b0);
    b0 = bn;
    bn = loadB(Et, t0 + 3, w, lg, c16);
    COMP(2, b0);
    b0 = bn;
    if (nc < 15) bn = loadB(Et, t0 + 4, w, lg, c16);
    COMP(3, b0);
    b0 = bn;

    // epilogue: table is pre-normalized; pure register compare (cols ascend)
#pragma unroll
    for (int nf = 0; nf < 2; ++nf) {
      const int c = nc * 128 + w * 32 + nf * 16 + c16;
#pragma unroll
      for (int mf = 0; mf < 2; ++mf)
#pragma unroll
        for (int r = 0; r < 4; ++r) {
          const double s =
              (double)accm[mf][nf][r] + (double)accc[mf][nf][r] * (1.0 / 4096.0);
          if (s > best[mf][r]) { best[mf][r] = s; bidx[mf][r] = c; }
        }
    }
  }

  // ---- final reduction: 64 (wave, col-lane) entries per row
  __syncthreads();  // all waves done with xs region
  double* redD = (double*)lds;       // 32*64 doubles = 16 KB
  int* redI = (int*)(lds + 16384);   // 8 KB
  const int ent = w * 16 + c16;
#pragma unroll
  for (int mf = 0; mf < 2; ++mf)
#pragma unroll
    for (int r = 0; r < 4; ++r) {
      const int row = mf * 16 + lg * 4 + r;
      redD[row * 64 + ent] = best[mf][r];
      redI[row * 64 + ent] = bidx[mf][r];
    }
  __syncthreads();
  if (tid < 32) {
    double bd = -1e300;
    int bi = 1 << 30;
    for (int e = 0; e < 64; ++e) {
      double dv = redD[tid * 64 + e];
      int iv = redI[tid * 64 + e];
      if (dv > bd || (dv == bd && iv < bi)) { bd = dv; bi = iv; }
    }
    const int n = rowbase + tid;
    idx_ws[n] = bi;
    fidx_out[n] = (float)bi;
    atomicAdd(&counts[bi], 1);
  }
}

// ------------------------------------------------- gather + quantize + loss
__global__ __launch_bounds__(256) void k_quant(const float* __restrict__ x,
                                               const float* __restrict__ E,
                                               const int* __restrict__ idx,
                                               float* __restrict__ out,
                                               float* __restrict__ lossparts) {
  const int T = blockIdx.x * 256 + threadIdx.x;
  const int w4 = T & 7;
  int rest = T >> 3;
  const int h = rest & 31;
  rest >>= 5;
  const int d = rest & 255;
  const int b = rest >> 8;
  const int n = b * 1024 + h * 32 + w4 * 4;
  const int4 iv = *(const int4*)(idx + n);
  const size_t xoff = ((size_t)(b * 256 + d) << 10) + h * 32 + w4 * 4;
  const float4 xv = *(const float4*)(x + xoff);
  const float* Er = E + (size_t)d * KN;
  float4 q;
  q.x = Er[iv.x];
  q.y = Er[iv.y];
  q.z = Er[iv.z];
  q.w = Er[iv.w];
  *(float4*)(out + xoff) = q;
  const float dx = xv.x - q.x, dy = xv.y - q.y, dz = xv.z - q.z, dw = xv.w - q.w;
  float s = dx * dx + dy * dy + dz * dz + dw * dw;
#pragma unroll
  for (int off = 32; off > 0; off >>= 1) s += __shfl_down(s, off, 64);
  __shared__ float red[4];
  const int lane = threadIdx.x & 63, wv = threadIdx.x >> 6;
  if (lane == 0) red[wv] = s;
  __syncthreads();
  if (threadIdx.x == 0)
    atomicAdd(&lossparts[blockIdx.x & 255], red[0] + red[1] + red[2] + red[3]);
}

// -------------------------------------------------------- losses + entropy
__global__ __launch_bounds__(256) void k_final(const int* __restrict__ counts,
                                               const float* __restrict__ lossparts,
                                               float* __restrict__ out) {
  __shared__ double redE[256];
  __shared__ double redL[256];
  const int tid = threadIdx.x;
  double t = 0.0;
  for (int u = tid; u < KN; u += 256) {
    float p = (float)counts[u] * (1.0f / 32768.0f);
    t += (double)(p * logf(p + 1e-10f));
  }
  redE[tid] = t;
  redL[tid] = (double)lossparts[tid];
  __syncthreads();
  for (int s2 = 128; s2 > 0; s2 >>= 1) {
    if (tid < s2) {
      redE[tid] += redE[tid + s2];
      redL[tid] += redL[tid + s2];
    }
    __syncthreads();
  }
  if (tid == 0) {
    float L = (float)(redL[0] * (1.0 / 8388608.0));
    out[8388608] = L;  // dictionary_loss
    out[8388609] = L;  // commitment_loss (identical in forward)
    out[8388610] = (float)redE[0];
  }
}

extern "C" void kernel_launch(void* const* d_in, const int* in_sizes, int n_in,
                              void* d_out, int out_size, void* d_ws, size_t ws_size,
                              hipStream_t stream) {
  const float* x = (const float*)d_in[0];
  const float* E = (const float*)d_in[1];
  float* out = (float*)d_out;
  char* ws = (char*)d_ws;
  int* counts = (int*)ws;
  float* lossparts = (float*)(ws + 8192);
  double* norminv = (double*)(ws + 16384);
  int* idx = (int*)(ws + 32768);
  _Float16* Et = (_Float16*)(ws + 163840);

  hipMemsetAsync(ws, 0, 32768, stream);  // counts + lossparts + norminv
  k_norm<<<64, 256, 0, stream>>>(E, norminv);
  k_inv<<<8, 256, 0, stream>>>(norminv);
  k_convE<<<256, 256, 0, stream>>>(E, norminv, Et);
  k_score<<<NN / 32, 256, 0, stream>>>(x, Et, idx, out + 8388611, counts);
  k_quant<<<(NN * DN / 4) / 256, 256, 0, stream>>>(x, E, idx, out, lossparts);
  k_final<<<1, 256, 0, stream>>>(counts, lossparts, out);
}

// Round 6
// 232.106 us; speedup vs baseline: 5.8975x; 1.4203x over previous
//
#include <hip/hip_runtime.h>
#include <hip/hip_bf16.h>
#include <hip/hip_fp16.h>
#include <math.h>

// Problem constants
#define KN 2048      // num_embeddings (GEMM N)
#define DN 256       // embedding_dim  (GEMM K)
#define NN 32768     // B*H*W          (GEMM M)
#define HW 1024      // H*W
#define XSTR 260     // padded LDS row stride for x tile (floats)

typedef _Float16 half8 __attribute__((ext_vector_type(8)));
typedef float floatx4 __attribute__((ext_vector_type(4)));

// ws layout (bytes):
//   counts    int[2048]     @ 0        (zeroed each call)
//   lossparts float[256]    @ 8192     (zeroed each call)
//   norminv   double[2048]  @ 16384
//   idx       int[32768]    @ 32768
//   Et        f16[1048576]  @ 163840   (2 MB) tile-order, pre-normalized:
//     tile t = nc*8+kh (nc: 128-col group, kh: 32-d group), 8192 halfs:
//     [w:4][s:4][lane:64][j:8], s = {nf0 hi, nf1 hi, nf0 lo, nf1 lo},
//     lane = lg*16+col16, k-in-32 = lg*8+j, col = nc*128+w*32+nf*16+col16

// ------------------------------------------- column inv-norms (single pass)
__global__ __launch_bounds__(256) void k_norm(const float* __restrict__ E,
                                              double* __restrict__ norminv) {
  const int c = blockIdx.x * 256 + threadIdx.x;
  const float* p = E + c;
  double s = 0.0;
#pragma unroll 8
  for (int d = 0; d < DN; ++d) {
    double v = (double)p[(size_t)d * KN];
    s = fma(v, v, s);
  }
  double nr = sqrt(s);
  if (nr < 1e-12) nr = 1e-12;
  norminv[c] = 1.0 / nr;
}

// --------------------- E -> normalized f16 hi/lo, tile order (see ws map)
__global__ __launch_bounds__(256) void k_convE(const float* __restrict__ E,
                                               const double* __restrict__ norminv,
                                               _Float16* __restrict__ Et) {
  const int c = ((blockIdx.x & 7) << 8) + threadIdx.x;  // 0..2047
  const int dg = blockIdx.x >> 3;                       // 0..31 (8-d groups)
  const int kh = dg >> 2, lg = dg & 3;
  const int nc = c >> 7, w = (c >> 5) & 3, nf = (c >> 4) & 1, col16 = c & 15;
  const int t = nc * 8 + kh;
  const double inv = norminv[c];
  const size_t base =
      (size_t)t * 8192 + w * 2048 + nf * 512 + (lg * 16 + col16) * 8;
  half8 hv, lv;
#pragma unroll
  for (int j = 0; j < 8; ++j) {
    float v = (float)((double)E[(size_t)(dg * 8 + j) * KN + c] * inv);
    _Float16 h = (_Float16)v;
    hv[j] = h;
    lv[j] = (_Float16)((v - (float)h) * 4096.0f);
  }
  *(half8*)(Et + base) = hv;
  *(half8*)(Et + base + 1024) = lv;  // s_lo = s_hi + 2 -> +1024 halfs
}

// -------------------------------------------------- async global->LDS helper
__device__ __forceinline__ void gload_lds16(const void* g, void* l) {
  __builtin_amdgcn_global_load_lds(
      (const __attribute__((address_space(1))) unsigned int*)g,
      (__attribute__((address_space(3))) unsigned int*)l, 16, 0, 0);
}

// ----------------------------------------------- fused MFMA GEMM^3 + argmax
// grid 1024 x 256 thr (4 waves). Block: 32 rows x 2048 cols. 128 tiles of
// (128 cols x 32 d, hi+lo) = 16 KB; 4 LDS buffers, staged 3-deep with
// counted vmcnt (never 0 in steady state) + raw s_barrier per tile.
#define STAGE(t, buf)                                                        \
  {                                                                          \
    const size_t gb_ = (size_t)(t) * 8192;                                   \
    const int lb_ = (buf) * 16384;                                           \
    _Pragma("unroll") for (int q_ = 0; q_ < 4; ++q_)                         \
        gload_lds16(Et + gb_ + q_ * 2048 + tid * 8,                          \
                    lds + lb_ + q_ * 4096 + tid * 16);                       \
  }

#define ITER(nc, kh, WAITOP, DO_STAGE)                                       \
  {                                                                          \
    asm volatile(WAITOP ::: "memory");                                       \
    __builtin_amdgcn_s_barrier();                                            \
    __builtin_amdgcn_sched_barrier(0);                                       \
    const int t_ = (nc)*8 + (kh);                                            \
    if (DO_STAGE) { STAGE(t_ + 3, (t_ + 3) & 3); }                           \
    const char* wb_ = lds + (t_ & 3) * 16384 + w * 4096;                     \
    half8 bh_[2], bl_[2];                                                    \
    bh_[0] = *(const half8*)(wb_ + lane * 16);                               \
    bh_[1] = *(const half8*)(wb_ + 1024 + lane * 16);                        \
    bl_[0] = *(const half8*)(wb_ + 2048 + lane * 16);                        \
    bl_[1] = *(const half8*)(wb_ + 3072 + lane * 16);                        \
    __builtin_amdgcn_s_setprio(1);                                           \
    _Pragma("unroll") for (int mf_ = 0; mf_ < 2; ++mf_)                      \
        _Pragma("unroll") for (int nf_ = 0; nf_ < 2; ++nf_) {                \
      accm[mf_][nf_] = __builtin_amdgcn_mfma_f32_16x16x32_f16(               \
          ah[mf_][(kh)], bh_[nf_], accm[mf_][nf_], 0, 0, 0);                 \
      accc[mf_][nf_] = __builtin_amdgcn_mfma_f32_16x16x32_f16(               \
          ah[mf_][(kh)], bl_[nf_], accc[mf_][nf_], 0, 0, 0);                 \
      accc[mf_][nf_] = __builtin_amdgcn_mfma_f32_16x16x32_f16(               \
          al[mf_][(kh)], bh_[nf_], accc[mf_][nf_], 0, 0, 0);                 \
    }                                                                        \
    __builtin_amdgcn_s_setprio(0);                                           \
  }

#define ZEROACC                                                              \
  {                                                                          \
    _Pragma("unroll") for (int mf_ = 0; mf_ < 2; ++mf_)                      \
        _Pragma("unroll") for (int nf_ = 0; nf_ < 2; ++nf_) {                \
      accm[mf_][nf_] = (floatx4)0.0f;                                        \
      accc[mf_][nf_] = (floatx4)0.0f;                                        \
    }                                                                        \
  }

#define EPILOGUE(nc)                                                         \
  {                                                                          \
    _Pragma("unroll") for (int nf_ = 0; nf_ < 2; ++nf_) {                    \
      const int c_ = (nc)*128 + w * 32 + nf_ * 16 + c16;                     \
      _Pragma("unroll") for (int mf_ = 0; mf_ < 2; ++mf_)                    \
          _Pragma("unroll") for (int r_ = 0; r_ < 4; ++r_) {                 \
        const double s_ = (double)accm[mf_][nf_][r_] +                       \
                          (double)accc[mf_][nf_][r_] * (1.0 / 4096.0);       \
        if (s_ > best[mf_][r_]) { best[mf_][r_] = s_; bidx[mf_][r_] = c_; }  \
      }                                                                      \
    }                                                                        \
  }

#define W8 "s_waitcnt vmcnt(8)"
#define W4 "s_waitcnt vmcnt(4)"
#define W0 "s_waitcnt vmcnt(0)"

__global__ __launch_bounds__(256, 2) void k_score(
    const float* __restrict__ x, const _Float16* __restrict__ Et,
    int* __restrict__ idx_ws, float* __restrict__ fidx_out,
    int* __restrict__ counts) {
  __shared__ __align__(16) char lds[65536];
  const int tid = threadIdx.x;
  const int lane = tid & 63;
  const int w = tid >> 6;
  const int lg = lane >> 4;
  const int c16 = lane & 15;
  const int rowbase = blockIdx.x * 32;

  // ---- stage x tile (f32) into LDS [32][XSTR]
  {
    float* xs = (float*)lds;
    const int r = tid & 31;
    const int d0 = tid >> 5;
    const int n = rowbase + r;
    const float* xb = x + (size_t)(n >> 10) * (DN * HW) + (n & 1023);
#pragma unroll
    for (int d = d0; d < DN; d += 8)
      xs[r * XSTR + d] = xb[(size_t)d * HW];
  }
  __syncthreads();

  // ---- build A fragments: row=lane&15 (+16*mf), k = kh*32 + lg*8 + i
  half8 ah[2][8], al[2][8];
  {
    const float* xs = (const float*)lds;
#pragma unroll
    for (int mf = 0; mf < 2; ++mf)
#pragma unroll
      for (int kh = 0; kh < 8; ++kh) {
        const float* p = xs + (mf * 16 + c16) * XSTR + kh * 32 + lg * 8;
        half8 h, l;
#pragma unroll
        for (int i = 0; i < 8; ++i) {
          float v = p[i];
          _Float16 hh = (_Float16)v;
          h[i] = hh;
          l[i] = (_Float16)((v - (float)hh) * 4096.0f);
        }
        ah[mf][kh] = h;
        al[mf][kh] = l;
      }
  }
  __syncthreads();  // all waves done with xs; LDS becomes staging buffers

  double best[2][4];
  int bidx[2][4];
#pragma unroll
  for (int mf = 0; mf < 2; ++mf)
#pragma unroll
    for (int r = 0; r < 4; ++r) { best[mf][r] = -1e300; bidx[mf][r] = 0; }

  floatx4 accm[2][2], accc[2][2];

  // prologue: 3 tiles in flight (12 outstanding loads per thread)
  STAGE(0, 0);
  STAGE(1, 1);
  STAGE(2, 2);

  for (int nc = 0; nc < 15; ++nc) {
    ZEROACC;
    ITER(nc, 0, W8, 1);
    ITER(nc, 1, W8, 1);
    ITER(nc, 2, W8, 1);
    ITER(nc, 3, W8, 1);
    ITER(nc, 4, W8, 1);
    ITER(nc, 5, W8, 1);
    ITER(nc, 6, W8, 1);
    ITER(nc, 7, W8, 1);
    EPILOGUE(nc);
  }
  // nc = 15: stages end at t+3 = 127 (kh=4); waits taper 8 -> 4 -> 0
  ZEROACC;
  ITER(15, 0, W8, 1);
  ITER(15, 1, W8, 1);
  ITER(15, 2, W8, 1);
  ITER(15, 3, W8, 1);
  ITER(15, 4, W8, 1);
  ITER(15, 5, W8, 0);
  ITER(15, 6, W4, 0);
  ITER(15, 7, W0, 0);
  EPILOGUE(15);

  // ---- final reduction: 64 (wave, col-lane) entries per row
  __syncthreads();
  double* redD = (double*)lds;       // 32*64 doubles = 16 KB
  int* redI = (int*)(lds + 16384);   // 8 KB
  const int ent = w * 16 + c16;
#pragma unroll
  for (int mf = 0; mf < 2; ++mf)
#pragma unroll
    for (int r = 0; r < 4; ++r) {
      const int row = mf * 16 + lg * 4 + r;
      redD[row * 64 + ent] = best[mf][r];
      redI[row * 64 + ent] = bidx[mf][r];
    }
  __syncthreads();
  if (tid < 32) {
    double bd = -1e300;
    int bi = 1 << 30;
    for (int e = 0; e < 64; ++e) {
      double dv = redD[tid * 64 + e];
      int iv = redI[tid * 64 + e];
      if (dv > bd || (dv == bd && iv < bi)) { bd = dv; bi = iv; }
    }
    const int n = rowbase + tid;
    idx_ws[n] = bi;
    fidx_out[n] = (float)bi;
    atomicAdd(&counts[bi], 1);
  }
}

// ------------------------------------------------- gather + quantize + loss
__global__ __launch_bounds__(256) void k_quant(const float* __restrict__ x,
                                               const float* __restrict__ E,
                                               const int* __restrict__ idx,
                                               float* __restrict__ out,
                                               float* __restrict__ lossparts) {
  const int T = blockIdx.x * 256 + threadIdx.x;
  const int w4 = T & 7;
  int rest = T >> 3;
  const int h = rest & 31;
  rest >>= 5;
  const int d = rest & 255;
  const int b = rest >> 8;
  const int n = b * 1024 + h * 32 + w4 * 4;
  const int4 iv = *(const int4*)(idx + n);
  const size_t xoff = ((size_t)(b * 256 + d) << 10) + h * 32 + w4 * 4;
  const float4 xv = *(const float4*)(x + xoff);
  const float* Er = E + (size_t)d * KN;
  float4 q;
  q.x = Er[iv.x];
  q.y = Er[iv.y];
  q.z = Er[iv.z];
  q.w = Er[iv.w];
  *(float4*)(out + xoff) = q;
  const float dx = xv.x - q.x, dy = xv.y - q.y, dz = xv.z - q.z, dw = xv.w - q.w;
  float s = dx * dx + dy * dy + dz * dz + dw * dw;
#pragma unroll
  for (int off = 32; off > 0; off >>= 1) s += __shfl_down(s, off, 64);
  __shared__ float red[4];
  const int lane = threadIdx.x & 63, wv = threadIdx.x >> 6;
  if (lane == 0) red[wv] = s;
  __syncthreads();
  if (threadIdx.x == 0)
    atomicAdd(&lossparts[blockIdx.x & 255], red[0] + red[1] + red[2] + red[3]);
}

// -------------------------------------------------------- losses + entropy
__global__ __launch_bounds__(256) void k_final(const int* __restrict__ counts,
                                               const float* __restrict__ lossparts,
                                               float* __restrict__ out) {
  __shared__ double redE[256];
  __shared__ double redL[256];
  const int tid = threadIdx.x;
  double t = 0.0;
  for (int u = tid; u < KN; u += 256) {
    float p = (float)counts[u] * (1.0f / 32768.0f);
    t += (double)(p * logf(p + 1e-10f));
  }
  redE[tid] = t;
  redL[tid] = (double)lossparts[tid];
  __syncthreads();
  for (int s2 = 128; s2 > 0; s2 >>= 1) {
    if (tid < s2) {
      redE[tid] += redE[tid + s2];
      redL[tid] += redL[tid + s2];
    }
    __syncthreads();
  }
  if (tid == 0) {
    float L = (float)(redL[0] * (1.0 / 8388608.0));
    out[8388608] = L;  // dictionary_loss
    out[8388609] = L;  // commitment_loss (identical in forward)
    out[8388610] = (float)redE[0];
  }
}

extern "C" void kernel_launch(void* const* d_in, const int* in_sizes, int n_in,
                              void* d_out, int out_size, void* d_ws, size_t ws_size,
                              hipStream_t stream) {
  const float* x = (const float*)d_in[0];
  const float* E = (const float*)d_in[1];
  float* out = (float*)d_out;
  char* ws = (char*)d_ws;
  int* counts = (int*)ws;
  float* lossparts = (float*)(ws + 8192);
  double* norminv = (double*)(ws + 16384);
  int* idx = (int*)(ws + 32768);
  _Float16* Et = (_Float16*)(ws + 163840);

  hipMemsetAsync(ws, 0, 9216, stream);  // counts + lossparts
  k_norm<<<8, 256, 0, stream>>>(E, norminv);
  k_convE<<<256, 256, 0, stream>>>(E, norminv, Et);
  k_score<<<NN / 32, 256, 0, stream>>>(x, Et, idx, out + 8388611, counts);
  k_quant<<<(NN * DN / 4) / 256, 256, 0, stream>>>(x, E, idx, out, lossparts);
  k_final<<<1, 256, 0, stream>>>(counts, lossparts, out);
}